// Round 2
// baseline (1511.956 us; speedup 1.0000x reference)
//
#include <hip/hip_runtime.h>
#include <cstdint>

using u16 = unsigned short;
using u32 = unsigned int;

typedef __bf16 bf16x8 __attribute__((ext_vector_type(8)));
typedef float  floatx4 __attribute__((ext_vector_type(4)));

#define DEV static __device__ __forceinline__

// ---------- helpers ----------
DEV u16 f2bf(float f) {                 // f32 -> bf16 RNE
    u32 u = __float_as_uint(f);
    u += 0x7FFFu + ((u >> 16) & 1u);
    return (u16)(u >> 16);
}
DEV float bf2f(u16 v) { return __uint_as_float(((u32)v) << 16); }

DEV floatx4 mfma32(bf16x8 a, bf16x8 b, floatx4 c) {
    return __builtin_amdgcn_mfma_f32_16x16x32_bf16(a, b, c, 0, 0, 0);
}

DEV floatx4 fzero() { floatx4 z; z[0]=0.f; z[1]=0.f; z[2]=0.f; z[3]=0.f; return z; }

// ---------- weight transpose: W[K][N] f32 -> Wt[N][K] bf16 ----------
__global__ __launch_bounds__(256) void transpose_w(
    const float* __restrict__ W, u16* __restrict__ Wt, int K, int N)
{
    __shared__ float t[32][33];
    const int tx = threadIdx.x, ty = threadIdx.y;   // block 32x8
    const int gx = blockIdx.x * 32;                 // N dim
    const int gy = blockIdx.y * 32;                 // K dim
    #pragma unroll
    for (int i = 0; i < 4; ++i)
        t[ty + i*8][tx] = W[(size_t)(gy + ty + i*8) * N + gx + tx];
    __syncthreads();
    #pragma unroll
    for (int i = 0; i < 4; ++i)
        Wt[(size_t)(gx + ty + i*8) * K + gy + tx] = f2bf(t[tx][ty + i*8]);
}

// ---------- LayerNorm (wave per row, 4 rows/block), writes bf16 ----------
// MODE 0: temporal  src = x[row + row/3136 + 1] f32   (x skip-cls order)
// MODE 1: spatial   row=(bt,p); p==0 -> x[b0,0] f32; else xt2 bf16 [b0*3136+(p-1)*16+tt]
template<int MODE>
__global__ __launch_bounds__(256) void ln_kernel(
    const float* __restrict__ xp, const u16* __restrict__ xt2,
    const float* __restrict__ w, const float* __restrict__ b,
    u16* __restrict__ out, int nrows)
{
    const int row = blockIdx.x * 4 + (threadIdx.x >> 6);
    if (row >= nrows) return;
    const int lane = threadIdx.x & 63;
    float vals[12];
    if constexpr (MODE == 0) {
        const float* src = xp + (size_t)(row + row/3136 + 1) * 768;
        #pragma unroll
        for (int j = 0; j < 3; ++j) {
            float4 v = reinterpret_cast<const float4*>(src)[j*64 + lane];
            vals[j*4+0]=v.x; vals[j*4+1]=v.y; vals[j*4+2]=v.z; vals[j*4+3]=v.w;
        }
    } else {
        const int bt = row / 197;
        const int p  = row - bt * 197;
        const int b0 = bt >> 4, tt = bt & 15;
        if (p == 0) {
            const float* src = xp + (size_t)b0 * 3137 * 768;
            #pragma unroll
            for (int j = 0; j < 3; ++j) {
                float4 v = reinterpret_cast<const float4*>(src)[j*64 + lane];
                vals[j*4+0]=v.x; vals[j*4+1]=v.y; vals[j*4+2]=v.z; vals[j*4+3]=v.w;
            }
        } else {
            const u16* src = xt2 + (size_t)(b0*3136 + (p-1)*16 + tt) * 768;
            #pragma unroll
            for (int j = 0; j < 3; ++j) {
                uint2 q = reinterpret_cast<const uint2*>(src)[j*64 + lane];
                vals[j*4+0] = bf2f((u16)(q.x & 0xFFFF));
                vals[j*4+1] = bf2f((u16)(q.x >> 16));
                vals[j*4+2] = bf2f((u16)(q.y & 0xFFFF));
                vals[j*4+3] = bf2f((u16)(q.y >> 16));
            }
        }
    }
    float s = 0.f, ss = 0.f;
    #pragma unroll
    for (int e = 0; e < 12; ++e) { s += vals[e]; ss += vals[e]*vals[e]; }
    #pragma unroll
    for (int o = 32; o > 0; o >>= 1) { s += __shfl_xor(s, o); ss += __shfl_xor(ss, o); }
    const float mean = s * (1.f/768.f);
    const float var  = ss * (1.f/768.f) - mean*mean;
    const float rstd = rsqrtf(var + 1e-5f);
    #pragma unroll
    for (int j = 0; j < 3; ++j) {
        const int c4 = (j*64 + lane) * 4;
        union { u16 u[4]; uint2 q; } o;
        #pragma unroll
        for (int e = 0; e < 4; ++e)
            o.u[e] = f2bf((vals[j*4+e] - mean)*rstd*w[c4+e] + b[c4+e]);
        *reinterpret_cast<uint2*>(&out[(size_t)row*768 + c4]) = o.q;
    }
}

// ---------- combine: x_new = concat residuals (f32 -> d_out), then LN(n2) bf16 ----------
__global__ __launch_bounds__(256) void combine_ln2(
    const float* __restrict__ xp, const u16* __restrict__ xt2,
    const u16* __restrict__ rsb, const float* __restrict__ w, const float* __restrict__ b,
    float* __restrict__ xnew, u16* __restrict__ ln2, int nrows)
{
    const int row = blockIdx.x * 4 + (threadIdx.x >> 6);
    if (row >= nrows) return;
    const int lane = threadIdx.x & 63;
    const int b0 = row / 3137;
    const int j  = row - b0 * 3137;
    float vals[12];
    if (j == 0) {       // cls row: x[b,0] + mean_t rs[(b,t) seq, token 0]
        #pragma unroll
        for (int e = 0; e < 12; ++e) {
            const int c = e*64 + lane;
            float acc = 0.f;
            for (int t = 0; t < 16; ++t)
                acc += bf2f(rsb[(size_t)(b0*16 + t) * 197 * 768 + c]);
            vals[e] = xp[(size_t)row*768 + c] + acc * (1.f/16.f);
        }
    } else {
        const int n_idx = j - 1;
        const int hw = n_idx >> 4, tt = n_idx & 15;
        const u16* a  = xt2 + (size_t)(b0*3136 + n_idx) * 768;
        const u16* r2 = rsb + (size_t)((b0*16 + tt)*197 + 1 + hw) * 768;
        #pragma unroll
        for (int e = 0; e < 12; ++e) {
            const int c = e*64 + lane;
            vals[e] = bf2f(a[c]) + bf2f(r2[c]);
        }
    }
    float s = 0.f, ss = 0.f;
    #pragma unroll
    for (int e = 0; e < 12; ++e) { s += vals[e]; ss += vals[e]*vals[e]; }
    #pragma unroll
    for (int o = 32; o > 0; o >>= 1) { s += __shfl_xor(s, o); ss += __shfl_xor(ss, o); }
    const float mean = s * (1.f/768.f);
    const float var  = ss * (1.f/768.f) - mean*mean;
    const float rstd = rsqrtf(var + 1e-5f);
    #pragma unroll
    for (int e = 0; e < 12; ++e) {
        const int c = e*64 + lane;
        xnew[(size_t)row*768 + c] = vals[e];
        ln2[(size_t)row*768 + c]  = f2bf((vals[e] - mean)*rstd*w[c] + b[c]);
    }
}

// ---------- GEMM: C[M,N] = act(A[M,K]bf16 @ B + bias (+resid)) ----------
// Bt is B^T bf16 [N][ldb]. 128x128 tile, BK=32, 4 waves of 4x4 16x16x32 MFMAs.
// Register staging (m93-style): uint4 global loads -> regs -> ds_write_b128.
// RESID: 0 none, 1 f32 resid[row*N+col], 2 f32 x-skip-cls resid[(row+row/3136+1)*768+col]
template<int RESID, bool BIAS, bool GELU_ACT, bool OUTF, bool OUTB, bool MASKM>
__global__ __launch_bounds__(256) void gemm_bt(
    const u16* __restrict__ A, const u16* __restrict__ Bt,
    const float* __restrict__ bias, const float* __restrict__ resid,
    float* __restrict__ Cf, u16* __restrict__ Cb,
    int N, int K, int lda, int ldb, int Mvalid)
{
    __shared__ __attribute__((aligned(16))) u16 As[128*32];
    __shared__ __attribute__((aligned(16))) u16 Bs[128*32];
    const int tid  = threadIdx.x;
    const int wave = tid >> 6;
    const int lane = tid & 63;
    const int m15  = lane & 15;
    const int quad = lane >> 4;
    const int wm = wave >> 1, wn = wave & 1;
    const long m0 = (long)blockIdx.x * 128;
    const long n0 = (long)blockIdx.y * 128;

    // staging: 512 16B-chunks per tile; chunk c: row=c>>2, col8=(c&3)*8
    const int c0 = wave*128 + lane;
    const int c1 = wave*128 + 64 + lane;
    const u16* Ag0 = A  + (size_t)(m0 + (c0 >> 2)) * lda + (c0 & 3) * 8;
    const u16* Ag1 = A  + (size_t)(m0 + (c1 >> 2)) * lda + (c1 & 3) * 8;
    const u16* Bg0 = Bt + (size_t)(n0 + (c0 >> 2)) * ldb + (c0 & 3) * 8;
    const u16* Bg1 = Bt + (size_t)(n0 + (c1 >> 2)) * ldb + (c1 & 3) * 8;
    u16* Al0 = &As[(size_t)c0 * 8];
    u16* Al1 = &As[(size_t)c1 * 8];
    u16* Bl0 = &Bs[(size_t)c0 * 8];
    u16* Bl1 = &Bs[(size_t)c1 * 8];

    floatx4 acc[4][4];
    #pragma unroll
    for (int i = 0; i < 4; ++i)
        #pragma unroll
        for (int j = 0; j < 4; ++j) acc[i][j] = fzero();

    for (int k0 = 0; k0 < K; k0 += 32) {
        const uint4 ra0 = *reinterpret_cast<const uint4*>(Ag0 + k0);
        const uint4 ra1 = *reinterpret_cast<const uint4*>(Ag1 + k0);
        const uint4 rb0 = *reinterpret_cast<const uint4*>(Bg0 + k0);
        const uint4 rb1 = *reinterpret_cast<const uint4*>(Bg1 + k0);
        __syncthreads();                       // previous tile's reads done
        *reinterpret_cast<uint4*>(Al0) = ra0;
        *reinterpret_cast<uint4*>(Al1) = ra1;
        *reinterpret_cast<uint4*>(Bl0) = rb0;
        *reinterpret_cast<uint4*>(Bl1) = rb1;
        __syncthreads();                       // tiles visible
        bf16x8 af[4], bf[4];
        #pragma unroll
        for (int i = 0; i < 4; ++i)
            af[i] = *reinterpret_cast<const bf16x8*>(&As[(wm*64 + i*16 + m15)*32 + quad*8]);
        #pragma unroll
        for (int j = 0; j < 4; ++j)
            bf[j] = *reinterpret_cast<const bf16x8*>(&Bs[(wn*64 + j*16 + m15)*32 + quad*8]);
        #pragma unroll
        for (int i = 0; i < 4; ++i)
            #pragma unroll
            for (int j = 0; j < 4; ++j)
                acc[i][j] = mfma32(af[i], bf[j], acc[i][j]);
    }

    // epilogue: D row=(quad*4+r), col=lane&15 within each 16x16 tile
    #pragma unroll
    for (int j = 0; j < 4; ++j) {
        const long col = n0 + wn*64 + j*16 + m15;
        float bv = 0.f;
        if constexpr (BIAS) bv = bias[col];
        #pragma unroll
        for (int i = 0; i < 4; ++i) {
            const long rowb = m0 + wm*64 + i*16 + quad*4;
            #pragma unroll
            for (int r = 0; r < 4; ++r) {
                const long row = rowb + r;
                if constexpr (MASKM) { if (row >= Mvalid) continue; }
                float v = acc[i][j][r] + bv;
                if constexpr (RESID == 1) v += resid[(size_t)row * N + col];
                if constexpr (RESID == 2) v += resid[(size_t)(row + row/3136 + 1) * 768 + col];
                if constexpr (GELU_ACT)   v = 0.5f * v * (1.f + erff(v * 0.70710678118f));
                if constexpr (OUTF) Cf[(size_t)row * N + col] = v;
                if constexpr (OUTB) Cb[(size_t)row * N + col] = f2bf(v);
            }
        }
    }
}

// ---------- fused attention (flash-style), one wave per (seq, head, q-tile) ----------
// qkv rows: seq*S + token, row stride 2304, cols [q|k|v] each head*64+d.
// S^T = K·Q^T: lane holds S[key=quad*4+r(+h2*16)][query=lane&15] == need LDS
// round-trip to A-operand layout for PV.
template<int S, int NQ, int NIT>
__global__ __launch_bounds__(256) void attn_kernel(
    const u16* __restrict__ qkv, u16* __restrict__ out, int ntask)
{
    __shared__ __attribute__((aligned(16))) u16 P_lds[4][16*32];
    const int wave = threadIdx.x >> 6;
    const int lane = threadIdx.x & 63;
    const int task = blockIdx.x * 4 + wave;
    if (task >= ntask) return;
    const int seq  = task / (12 * NQ);
    const int rem  = task - seq * (12 * NQ);
    const int head = rem / NQ;
    const int qt   = rem - head * NQ;
    const int m15  = lane & 15;
    const int quad = lane >> 4;
    const size_t base = (size_t)seq * S;

    const u16* qp = qkv + (base + qt*16 + m15) * 2304 + head*64 + quad*8;
    const bf16x8 Qf0 = *reinterpret_cast<const bf16x8*>(qp);
    const bf16x8 Qf1 = *reinterpret_cast<const bf16x8*>(qp + 32);

    floatx4 Oacc[4];
    #pragma unroll
    for (int c = 0; c < 4; ++c) Oacc[c] = fzero();
    float mrun = -__builtin_inff();
    float lrun = 0.f;
    u16* P = &P_lds[wave][0];

    for (int it = 0; it < NIT; ++it) {
        const int j0 = it * 32;
        floatx4 st[2];
        #pragma unroll
        for (int h2 = 0; h2 < 2; ++h2) {
            const u16* kp = qkv + (base + j0 + h2*16 + m15) * 2304 + 768 + head*64 + quad*8;
            const bf16x8 K0 = *reinterpret_cast<const bf16x8*>(kp);
            const bf16x8 K1 = *reinterpret_cast<const bf16x8*>(kp + 32);
            floatx4 z = fzero();
            z = mfma32(K0, Qf0, z);
            st[h2] = mfma32(K1, Qf1, z);
        }
        float sc[8];
        #pragma unroll
        for (int h2 = 0; h2 < 2; ++h2)
            #pragma unroll
            for (int r = 0; r < 4; ++r) {
                const int jj = j0 + h2*16 + quad*4 + r;
                sc[h2*4+r] = (jj < S) ? st[h2][r] * 0.125f : -__builtin_inff();
            }
        float tmax = sc[0];
        #pragma unroll
        for (int k = 1; k < 8; ++k) tmax = fmaxf(tmax, sc[k]);
        tmax = fmaxf(tmax, __shfl_xor(tmax, 16));
        tmax = fmaxf(tmax, __shfl_xor(tmax, 32));
        const float mnew = fmaxf(mrun, tmax);
        float p[8], tsum = 0.f;
        #pragma unroll
        for (int k = 0; k < 8; ++k) { p[k] = __expf(sc[k] - mnew); tsum += p[k]; }
        tsum += __shfl_xor(tsum, 16);
        tsum += __shfl_xor(tsum, 32);
        const float alpha = __expf(mrun - mnew);
        lrun = lrun * alpha + tsum;
        mrun = mnew;
        #pragma unroll
        for (int r = 0; r < 4; ++r) {             // rescale O rows (row = quad*4+r)
            const float ar = __shfl(alpha, quad*4 + r);
            #pragma unroll
            for (int c = 0; c < 4; ++c) Oacc[c][r] *= ar;
        }
        // P round-trip through LDS: C-layout -> A-operand layout
        #pragma unroll
        for (int h2 = 0; h2 < 2; ++h2)
            #pragma unroll
            for (int r = 0; r < 4; ++r)
                P[m15*32 + h2*16 + quad*4 + r] = f2bf(p[h2*4+r]);
        const bf16x8 Pf = *reinterpret_cast<const bf16x8*>(&P[m15*32 + quad*8]);
        #pragma unroll
        for (int c = 0; c < 4; ++c) {             // V in B-operand layout (scattered u16)
            union { u16 u[8]; bf16x8 v; } vf;
            #pragma unroll
            for (int jj2 = 0; jj2 < 8; ++jj2)
                vf.u[jj2] = qkv[(base + j0 + quad*8 + jj2) * 2304 + 1536 + head*64 + c*16 + m15];
            Oacc[c] = mfma32(Pf, vf.v, Oacc[c]);
        }
    }
    const float linv_self = 1.f / lrun;
    #pragma unroll
    for (int r = 0; r < 4; ++r) {
        const int prow = qt*16 + quad*4 + r;
        const float linv = __shfl(linv_self, quad*4 + r);
        if (prow < S) {
            u16* op = out + (base + prow) * 768 + head*64 + m15;
            #pragma unroll
            for (int c = 0; c < 4; ++c) op[c*16] = f2bf(Oacc[c][r] * linv);
        }
    }
}

// ---------- host ----------
extern "C" void kernel_launch(void* const* d_in, const int* in_sizes, int n_in,
                              void* d_out, int out_size, void* d_ws, size_t ws_size,
                              hipStream_t stream)
{
    (void)in_sizes; (void)n_in; (void)out_size; (void)ws_size;
    const float* x        = (const float*)d_in[0];
    const float* tn1_w    = (const float*)d_in[1];
    const float* tn1_b    = (const float*)d_in[2];
    const float* t_qkv_w  = (const float*)d_in[3];
    const float* t_proj_w = (const float*)d_in[4];
    const float* t_proj_b = (const float*)d_in[5];
    const float* tfc_w    = (const float*)d_in[6];
    const float* tfc_b    = (const float*)d_in[7];
    const float* n1_w     = (const float*)d_in[8];
    const float* n1_b     = (const float*)d_in[9];
    const float* s_qkv_w  = (const float*)d_in[10];
    const float* s_proj_w = (const float*)d_in[11];
    const float* s_proj_b = (const float*)d_in[12];
    const float* n2_w     = (const float*)d_in[13];
    const float* n2_b     = (const float*)d_in[14];
    const float* fc1_w    = (const float*)d_in[15];
    const float* fc1_b    = (const float*)d_in[16];
    const float* fc2_w    = (const float*)d_in[17];
    const float* fc2_b    = (const float*)d_in[18];
    float* out = (float*)d_out;

    char* ws = (char*)d_ws;
    size_t off = 0;
    auto alloc = [&](size_t bytes) -> void* {
        void* p = ws + off;
        off += (bytes + 255) & ~(size_t)255;
        return p;
    };
    // weights (bf16, transposed to [N][K])           total ~20.1 MB
    u16* wt_tqkv  = (u16*)alloc((size_t)768*2304*2);
    u16* wt_tproj = (u16*)alloc((size_t)768*768*2);
    u16* wt_tfc   = (u16*)alloc((size_t)768*768*2);
    u16* wt_sqkv  = (u16*)alloc((size_t)768*2304*2);
    u16* wt_sproj = (u16*)alloc((size_t)768*768*2);
    u16* wt_fc1   = (u16*)alloc((size_t)768*3072*2);
    u16* wt_fc2   = (u16*)alloc((size_t)3072*768*2);
    // activation slots (aliased lifetimes)            total ~233 MB
    u16* slotA = (u16*)alloc((size_t)25280*2304*2);  // qkv_t / qkv_s / h1 halves (116.5 MB)
    u16* slotB = (u16*)alloc((size_t)25216*768*2);   // xt2 bf16 (38.7 MB)
    u16* slotD = (u16*)alloc((size_t)25216*768*2);   // ln_t/attn_t/ln_s/attn_s/ln2 (38.7 MB)
    u16* slotE = (u16*)alloc((size_t)25216*768*2);   // hp / rs bf16 (38.7 MB)
    // grand total ~252.8 MB; x_new lives in d_out (f32)

    dim3 tb(32, 8);
    transpose_w<<<dim3(72, 24), tb, 0, stream>>>(t_qkv_w,  wt_tqkv,  768, 2304);
    transpose_w<<<dim3(24, 24), tb, 0, stream>>>(t_proj_w, wt_tproj, 768, 768);
    transpose_w<<<dim3(24, 24), tb, 0, stream>>>(tfc_w,    wt_tfc,   768, 768);
    transpose_w<<<dim3(72, 24), tb, 0, stream>>>(s_qkv_w,  wt_sqkv,  768, 2304);
    transpose_w<<<dim3(24, 24), tb, 0, stream>>>(s_proj_w, wt_sproj, 768, 768);
    transpose_w<<<dim3(96, 24), tb, 0, stream>>>(fc1_w,    wt_fc1,   768, 3072);
    transpose_w<<<dim3(24, 96), tb, 0, stream>>>(fc2_w,    wt_fc2,   3072, 768);

    u16* lnT  = slotD;
    u16* qkvT = slotA;
    ln_kernel<0><<<25088/4, 256, 0, stream>>>(x, nullptr, tn1_w, tn1_b, lnT, 25088);
    gemm_bt<0,false,false,false,true,false><<<dim3(196,18), 256, 0, stream>>>(
        lnT, wt_tqkv, nullptr, nullptr, nullptr, qkvT, 2304, 768, 768, 768, 0);

    u16* attnT = slotD;
    attn_kernel<16,1,1><<<18816/4, 256, 0, stream>>>(qkvT, attnT, 18816);

    u16* hp = slotE;
    gemm_bt<0,true,false,false,true,false><<<dim3(196,6), 256, 0, stream>>>(
        attnT, wt_tproj, t_proj_b, nullptr, nullptr, hp, 768, 768, 768, 768, 0);

    u16* xt2 = slotB;   // tfc + bias + x-residual (skip-cls map) -> bf16
    gemm_bt<2,true,false,false,true,false><<<dim3(196,6), 256, 0, stream>>>(
        hp, wt_tfc, tfc_b, x, nullptr, xt2, 768, 768, 768, 768, 0);

    u16* lnS = slotD;
    ln_kernel<1><<<25216/4, 256, 0, stream>>>(x, xt2, n1_w, n1_b, lnS, 25216);

    u16* qkvS = slotA;
    gemm_bt<0,false,false,false,true,false><<<dim3(197,18), 256, 0, stream>>>(
        lnS, wt_sqkv, nullptr, nullptr, nullptr, qkvS, 2304, 768, 768, 768, 0);

    u16* attnS = slotD;
    attn_kernel<197,13,7><<<19968/4, 256, 0, stream>>>(qkvS, attnS, 19968);

    u16* rsb = slotE;
    gemm_bt<0,true,false,false,true,false><<<dim3(197,6), 256, 0, stream>>>(
        attnS, wt_sproj, s_proj_b, nullptr, nullptr, rsb, 768, 768, 768, 768, 0);

    float* xnew = out;                // x_new lives in d_out
    u16* ln2 = slotD;
    combine_ln2<<<25096/4, 256, 0, stream>>>(x, xt2, rsb, n2_w, n2_b, xnew, ln2, 25096);

    // MLP split into two hidden halves (h1 fits in slotA: 77.5 MB)
    u16* h1 = slotA;
    for (int half = 0; half < 2; ++half) {
        const u16* w1h = wt_fc1 + (size_t)half * 1536 * 768;   // rows [N-half][768]
        const float* b1h = fc1_b + half * 1536;
        gemm_bt<0,true,true,false,true,false><<<dim3(197,12), 256, 0, stream>>>(
            ln2, w1h, b1h, nullptr, nullptr, h1, 1536, 768, 768, 768, 0);
        const u16* w2h = wt_fc2 + (size_t)half * 1536;         // [768][3072] K-offset
        // out = (half==0 ? xnew : out) + y_half ; fc2 bias only once (half 0)
        if (half == 0)
            gemm_bt<1,true,false,true,false,true><<<dim3(197,6), 256, 0, stream>>>(
                h1, w2h, fc2_b, out, out, nullptr, 768, 1536, 1536, 3072, 25096);
        else
            gemm_bt<1,false,false,true,false,true><<<dim3(197,6), 256, 0, stream>>>(
                h1, w2h, nullptr, out, out, nullptr, 768, 1536, 1536, 3072, 25096);
    }
}

// Round 3
// 1471.436 us; speedup vs baseline: 1.0275x; 1.0275x over previous
//
#include <hip/hip_runtime.h>
#include <cstdint>

using u16 = unsigned short;
using u32 = unsigned int;

typedef __bf16 bf16x8 __attribute__((ext_vector_type(8)));
typedef float  floatx4 __attribute__((ext_vector_type(4)));

#define DEV static __device__ __forceinline__

// ---------- helpers ----------
DEV u16 f2bf(float f) {                 // f32 -> bf16 RNE
    u32 u = __float_as_uint(f);
    u += 0x7FFFu + ((u >> 16) & 1u);
    return (u16)(u >> 16);
}
DEV float bf2f(u16 v) { return __uint_as_float(((u32)v) << 16); }

DEV floatx4 mfma32(bf16x8 a, bf16x8 b, floatx4 c) {
    return __builtin_amdgcn_mfma_f32_16x16x32_bf16(a, b, c, 0, 0, 0);
}

DEV floatx4 fzero() { floatx4 z; z[0]=0.f; z[1]=0.f; z[2]=0.f; z[3]=0.f; return z; }

typedef __attribute__((address_space(3))) u32 as3_u32;
typedef __attribute__((address_space(1))) u32 as1_u32;

// async global->LDS, 16B per lane; LDS dest = wave-uniform base + lane*16.
// NOTE: direct C-style pointer casts = addrspacecast (strips LDS aperture).
// Casting through uintptr_t keeps aperture bits -> fault (round-1 bug).
DEV void async_ld16(const u16* g, u16* l) {
    __builtin_amdgcn_global_load_lds(
        (const as1_u32*)g, (as3_u32*)l, 16, 0, 0);
}

// ---------- weight transpose: W[K][N] f32 -> Wt[N][K] bf16 ----------
__global__ __launch_bounds__(256) void transpose_w(
    const float* __restrict__ W, u16* __restrict__ Wt, int K, int N)
{
    __shared__ float t[32][33];
    const int tx = threadIdx.x, ty = threadIdx.y;   // block 32x8
    const int gx = blockIdx.x * 32;                 // N dim
    const int gy = blockIdx.y * 32;                 // K dim
    #pragma unroll
    for (int i = 0; i < 4; ++i)
        t[ty + i*8][tx] = W[(size_t)(gy + ty + i*8) * N + gx + tx];
    __syncthreads();
    #pragma unroll
    for (int i = 0; i < 4; ++i)
        Wt[(size_t)(gx + ty + i*8) * K + gy + tx] = f2bf(t[tx][ty + i*8]);
}

// ---------- LayerNorm (wave per row, 4 rows/block), writes bf16 ----------
// MODE 0: temporal  src = x[row + row/3136 + 1] f32   (x skip-cls order)
// MODE 1: spatial   row=(bt,p); p==0 -> x[b0,0] f32; else xt2 bf16 [b0*3136+(p-1)*16+tt]
template<int MODE>
__global__ __launch_bounds__(256) void ln_kernel(
    const float* __restrict__ xp, const u16* __restrict__ xt2,
    const float* __restrict__ w, const float* __restrict__ b,
    u16* __restrict__ out, int nrows)
{
    const int row = blockIdx.x * 4 + (threadIdx.x >> 6);
    if (row >= nrows) return;
    const int lane = threadIdx.x & 63;
    float vals[12];
    if constexpr (MODE == 0) {
        const float* src = xp + (size_t)(row + row/3136 + 1) * 768;
        #pragma unroll
        for (int j = 0; j < 3; ++j) {
            float4 v = reinterpret_cast<const float4*>(src)[j*64 + lane];
            vals[j*4+0]=v.x; vals[j*4+1]=v.y; vals[j*4+2]=v.z; vals[j*4+3]=v.w;
        }
    } else {
        const int bt = row / 197;
        const int p  = row - bt * 197;
        const int b0 = bt >> 4, tt = bt & 15;
        if (p == 0) {
            const float* src = xp + (size_t)b0 * 3137 * 768;
            #pragma unroll
            for (int j = 0; j < 3; ++j) {
                float4 v = reinterpret_cast<const float4*>(src)[j*64 + lane];
                vals[j*4+0]=v.x; vals[j*4+1]=v.y; vals[j*4+2]=v.z; vals[j*4+3]=v.w;
            }
        } else {
            const u16* src = xt2 + (size_t)(b0*3136 + (p-1)*16 + tt) * 768;
            #pragma unroll
            for (int j = 0; j < 3; ++j) {
                uint2 q = reinterpret_cast<const uint2*>(src)[j*64 + lane];
                vals[j*4+0] = bf2f((u16)(q.x & 0xFFFF));
                vals[j*4+1] = bf2f((u16)(q.x >> 16));
                vals[j*4+2] = bf2f((u16)(q.y & 0xFFFF));
                vals[j*4+3] = bf2f((u16)(q.y >> 16));
            }
        }
    }
    float s = 0.f, ss = 0.f;
    #pragma unroll
    for (int e = 0; e < 12; ++e) { s += vals[e]; ss += vals[e]*vals[e]; }
    #pragma unroll
    for (int o = 32; o > 0; o >>= 1) { s += __shfl_xor(s, o); ss += __shfl_xor(ss, o); }
    const float mean = s * (1.f/768.f);
    const float var  = ss * (1.f/768.f) - mean*mean;
    const float rstd = rsqrtf(var + 1e-5f);
    #pragma unroll
    for (int j = 0; j < 3; ++j) {
        const int c4 = (j*64 + lane) * 4;
        union { u16 u[4]; uint2 q; } o;
        #pragma unroll
        for (int e = 0; e < 4; ++e)
            o.u[e] = f2bf((vals[j*4+e] - mean)*rstd*w[c4+e] + b[c4+e]);
        *reinterpret_cast<uint2*>(&out[(size_t)row*768 + c4]) = o.q;
    }
}

// ---------- combine: x_new = concat residuals (f32 -> d_out), then LN(n2) bf16 ----------
__global__ __launch_bounds__(256) void combine_ln2(
    const float* __restrict__ xp, const u16* __restrict__ xt2,
    const u16* __restrict__ rsb, const float* __restrict__ w, const float* __restrict__ b,
    float* __restrict__ xnew, u16* __restrict__ ln2, int nrows)
{
    const int row = blockIdx.x * 4 + (threadIdx.x >> 6);
    if (row >= nrows) return;
    const int lane = threadIdx.x & 63;
    const int b0 = row / 3137;
    const int j  = row - b0 * 3137;
    float vals[12];
    if (j == 0) {       // cls row: x[b,0] + mean_t rs[(b,t) seq, token 0]
        #pragma unroll
        for (int e = 0; e < 12; ++e) {
            const int c = e*64 + lane;
            float acc = 0.f;
            for (int t = 0; t < 16; ++t)
                acc += bf2f(rsb[(size_t)(b0*16 + t) * 197 * 768 + c]);
            vals[e] = xp[(size_t)row*768 + c] + acc * (1.f/16.f);
        }
    } else {
        const int n_idx = j - 1;
        const int hw = n_idx >> 4, tt = n_idx & 15;
        const u16* a  = xt2 + (size_t)(b0*3136 + n_idx) * 768;
        const u16* r2 = rsb + (size_t)((b0*16 + tt)*197 + 1 + hw) * 768;
        #pragma unroll
        for (int e = 0; e < 12; ++e) {
            const int c = e*64 + lane;
            vals[e] = bf2f(a[c]) + bf2f(r2[c]);
        }
    }
    float s = 0.f, ss = 0.f;
    #pragma unroll
    for (int e = 0; e < 12; ++e) { s += vals[e]; ss += vals[e]*vals[e]; }
    #pragma unroll
    for (int o = 32; o > 0; o >>= 1) { s += __shfl_xor(s, o); ss += __shfl_xor(ss, o); }
    const float mean = s * (1.f/768.f);
    const float var  = ss * (1.f/768.f) - mean*mean;
    const float rstd = rsqrtf(var + 1e-5f);
    #pragma unroll
    for (int e = 0; e < 12; ++e) {
        const int c = e*64 + lane;
        xnew[(size_t)row*768 + c] = vals[e];
        ln2[(size_t)row*768 + c]  = f2bf((vals[e] - mean)*rstd*w[c] + b[c]);
    }
}

// ---------- GEMM: C[M,N] = act(A[M,K]bf16 @ B + bias (+resid)) ----------
// Bt is B^T bf16 [N][ldb]. 128x128 tile, BK=32, 4 waves of 4x4 16x16x32 MFMAs.
// Async staging: global_load_lds width=16 (m97 structure).
// Grid: (N-tiles, M-tiles) -> consecutive blocks share the A-tile (L2-hot).
// RESID: 0 none, 1 f32 resid[row*N+col], 2 f32 x-skip-cls resid[(row+row/3136+1)*768+col]
template<int RESID, bool BIAS, bool GELU_ACT, bool OUTF, bool OUTB, bool MASKM>
__global__ __launch_bounds__(256) void gemm_bt(
    const u16* __restrict__ A, const u16* __restrict__ Bt,
    const float* __restrict__ bias, const float* __restrict__ resid,
    float* __restrict__ Cf, u16* __restrict__ Cb,
    int N, int K, int lda, int ldb, int Mvalid)
{
    __shared__ __attribute__((aligned(16))) u16 As[128*32];
    __shared__ __attribute__((aligned(16))) u16 Bs[128*32];
    const int tid  = threadIdx.x;
    const int wave = tid >> 6;
    const int lane = tid & 63;
    const int m15  = lane & 15;
    const int quad = lane >> 4;
    const int wm = wave >> 1, wn = wave & 1;
    const long m0 = (long)blockIdx.y * 128;   // M-tile (slow dim)
    const long n0 = (long)blockIdx.x * 128;   // N-tile (fast dim -> A reuse)

    // staging: 512 16B-chunks per tile; chunk c: row=c>>2, col8=(c&3)*8
    const int c0 = wave*128 + lane;
    const int c1 = wave*128 + 64 + lane;
    const u16* Ag0 = A  + (size_t)(m0 + (c0 >> 2)) * lda + (c0 & 3) * 8;
    const u16* Ag1 = A  + (size_t)(m0 + (c1 >> 2)) * lda + (c1 & 3) * 8;
    const u16* Bg0 = Bt + (size_t)(n0 + (c0 >> 2)) * ldb + (c0 & 3) * 8;
    const u16* Bg1 = Bt + (size_t)(n0 + (c1 >> 2)) * ldb + (c1 & 3) * 8;
    u16* Al0 = &As[(wave*2 + 0) * 512];       // + lane*16B implicit in DMA
    u16* Al1 = &As[(wave*2 + 1) * 512];
    u16* Bl0 = &Bs[(wave*2 + 0) * 512];
    u16* Bl1 = &Bs[(wave*2 + 1) * 512];

    floatx4 acc[4][4];
    #pragma unroll
    for (int i = 0; i < 4; ++i)
        #pragma unroll
        for (int j = 0; j < 4; ++j) acc[i][j] = fzero();

    for (int k0 = 0; k0 < K; k0 += 32) {
        __syncthreads();                       // previous tile's reads done
        async_ld16(Ag0 + k0, Al0);
        async_ld16(Ag1 + k0, Al1);
        async_ld16(Bg0 + k0, Bl0);
        async_ld16(Bg1 + k0, Bl1);
        __syncthreads();                       // drains vmcnt -> tiles visible
        bf16x8 af[4], bf[4];
        #pragma unroll
        for (int i = 0; i < 4; ++i)
            af[i] = *reinterpret_cast<const bf16x8*>(&As[(wm*64 + i*16 + m15)*32 + quad*8]);
        #pragma unroll
        for (int j = 0; j < 4; ++j)
            bf[j] = *reinterpret_cast<const bf16x8*>(&Bs[(wn*64 + j*16 + m15)*32 + quad*8]);
        #pragma unroll
        for (int i = 0; i < 4; ++i)
            #pragma unroll
            for (int j = 0; j < 4; ++j)
                acc[i][j] = mfma32(af[i], bf[j], acc[i][j]);
    }

    // epilogue: D row=(quad*4+r), col=lane&15 within each 16x16 tile
    #pragma unroll
    for (int j = 0; j < 4; ++j) {
        const long col = n0 + wn*64 + j*16 + m15;
        float bv = 0.f;
        if constexpr (BIAS) bv = bias[col];
        #pragma unroll
        for (int i = 0; i < 4; ++i) {
            const long rowb = m0 + wm*64 + i*16 + quad*4;
            #pragma unroll
            for (int r = 0; r < 4; ++r) {
                const long row = rowb + r;
                if constexpr (MASKM) { if (row >= Mvalid) continue; }
                float v = acc[i][j][r] + bv;
                if constexpr (RESID == 1) v += resid[(size_t)row * N + col];
                if constexpr (RESID == 2) v += resid[(size_t)(row + row/3136 + 1) * 768 + col];
                if constexpr (GELU_ACT)   v = 0.5f * v * (1.f + erff(v * 0.70710678118f));
                if constexpr (OUTF) Cf[(size_t)row * N + col] = v;
                if constexpr (OUTB) Cb[(size_t)row * N + col] = f2bf(v);
            }
        }
    }
}

// ---------- fused attention (flash-style), one wave per (seq, head, q-tile) ----------
template<int S, int NQ, int NIT>
__global__ __launch_bounds__(256) void attn_kernel(
    const u16* __restrict__ qkv, u16* __restrict__ out, int ntask)
{
    __shared__ __attribute__((aligned(16))) u16 P_lds[4][16*32];
    const int wave = threadIdx.x >> 6;
    const int lane = threadIdx.x & 63;
    const int task = blockIdx.x * 4 + wave;
    if (task >= ntask) return;
    const int seq  = task / (12 * NQ);
    const int rem  = task - seq * (12 * NQ);
    const int head = rem / NQ;
    const int qt   = rem - head * NQ;
    const int m15  = lane & 15;
    const int quad = lane >> 4;
    const size_t base = (size_t)seq * S;

    const u16* qp = qkv + (base + qt*16 + m15) * 2304 + head*64 + quad*8;
    const bf16x8 Qf0 = *reinterpret_cast<const bf16x8*>(qp);
    const bf16x8 Qf1 = *reinterpret_cast<const bf16x8*>(qp + 32);

    floatx4 Oacc[4];
    #pragma unroll
    for (int c = 0; c < 4; ++c) Oacc[c] = fzero();
    float mrun = -__builtin_inff();
    float lrun = 0.f;
    u16* P = &P_lds[wave][0];

    for (int it = 0; it < NIT; ++it) {
        const int j0 = it * 32;
        floatx4 st[2];
        #pragma unroll
        for (int h2 = 0; h2 < 2; ++h2) {
            const u16* kp = qkv + (base + j0 + h2*16 + m15) * 2304 + 768 + head*64 + quad*8;
            const bf16x8 K0 = *reinterpret_cast<const bf16x8*>(kp);
            const bf16x8 K1 = *reinterpret_cast<const bf16x8*>(kp + 32);
            floatx4 z = fzero();
            z = mfma32(K0, Qf0, z);
            st[h2] = mfma32(K1, Qf1, z);
        }
        float sc[8];
        #pragma unroll
        for (int h2 = 0; h2 < 2; ++h2)
            #pragma unroll
            for (int r = 0; r < 4; ++r) {
                const int jj = j0 + h2*16 + quad*4 + r;
                sc[h2*4+r] = (jj < S) ? st[h2][r] * 0.125f : -__builtin_inff();
            }
        float tmax = sc[0];
        #pragma unroll
        for (int k = 1; k < 8; ++k) tmax = fmaxf(tmax, sc[k]);
        tmax = fmaxf(tmax, __shfl_xor(tmax, 16));
        tmax = fmaxf(tmax, __shfl_xor(tmax, 32));
        const float mnew = fmaxf(mrun, tmax);
        float p[8], tsum = 0.f;
        #pragma unroll
        for (int k = 0; k < 8; ++k) { p[k] = __expf(sc[k] - mnew); tsum += p[k]; }
        tsum += __shfl_xor(tsum, 16);
        tsum += __shfl_xor(tsum, 32);
        const float alpha = __expf(mrun - mnew);
        lrun = lrun * alpha + tsum;
        mrun = mnew;
        #pragma unroll
        for (int r = 0; r < 4; ++r) {             // rescale O rows (row = quad*4+r)
            const float ar = __shfl(alpha, quad*4 + r);
            #pragma unroll
            for (int c = 0; c < 4; ++c) Oacc[c][r] *= ar;
        }
        // P round-trip through LDS: C-layout -> A-operand layout
        #pragma unroll
        for (int h2 = 0; h2 < 2; ++h2)
            #pragma unroll
            for (int r = 0; r < 4; ++r)
                P[m15*32 + h2*16 + quad*4 + r] = f2bf(p[h2*4+r]);
        const bf16x8 Pf = *reinterpret_cast<const bf16x8*>(&P[m15*32 + quad*8]);
        #pragma unroll
        for (int c = 0; c < 4; ++c) {             // V in B-operand layout (scattered u16)
            union { u16 u[8]; bf16x8 v; } vf;
            #pragma unroll
            for (int jj2 = 0; jj2 < 8; ++jj2)
                vf.u[jj2] = qkv[(base + j0 + quad*8 + jj2) * 2304 + 1536 + head*64 + c*16 + m15];
            Oacc[c] = mfma32(Pf, vf.v, Oacc[c]);
        }
    }
    const float linv_self = 1.f / lrun;
    #pragma unroll
    for (int r = 0; r < 4; ++r) {
        const int prow = qt*16 + quad*4 + r;
        const float linv = __shfl(linv_self, quad*4 + r);
        if (prow < S) {
            u16* op = out + (base + prow) * 768 + head*64 + m15;
            #pragma unroll
            for (int c = 0; c < 4; ++c) op[c*16] = f2bf(Oacc[c][r] * linv);
        }
    }
}

// ---------- host ----------
extern "C" void kernel_launch(void* const* d_in, const int* in_sizes, int n_in,
                              void* d_out, int out_size, void* d_ws, size_t ws_size,
                              hipStream_t stream)
{
    (void)in_sizes; (void)n_in; (void)out_size; (void)ws_size;
    const float* x        = (const float*)d_in[0];
    const float* tn1_w    = (const float*)d_in[1];
    const float* tn1_b    = (const float*)d_in[2];
    const float* t_qkv_w  = (const float*)d_in[3];
    const float* t_proj_w = (const float*)d_in[4];
    const float* t_proj_b = (const float*)d_in[5];
    const float* tfc_w    = (const float*)d_in[6];
    const float* tfc_b    = (const float*)d_in[7];
    const float* n1_w     = (const float*)d_in[8];
    const float* n1_b     = (const float*)d_in[9];
    const float* s_qkv_w  = (const float*)d_in[10];
    const float* s_proj_w = (const float*)d_in[11];
    const float* s_proj_b = (const float*)d_in[12];
    const float* n2_w     = (const float*)d_in[13];
    const float* n2_b     = (const float*)d_in[14];
    const float* fc1_w    = (const float*)d_in[15];
    const float* fc1_b    = (const float*)d_in[16];
    const float* fc2_w    = (const float*)d_in[17];
    const float* fc2_b    = (const float*)d_in[18];
    float* out = (float*)d_out;

    char* ws = (char*)d_ws;
    size_t off = 0;
    auto alloc = [&](size_t bytes) -> void* {
        void* p = ws + off;
        off += (bytes + 255) & ~(size_t)255;
        return p;
    };
    // weights (bf16, transposed to [N][K])           total ~20.1 MB
    u16* wt_tqkv  = (u16*)alloc((size_t)768*2304*2);
    u16* wt_tproj = (u16*)alloc((size_t)768*768*2);
    u16* wt_tfc   = (u16*)alloc((size_t)768*768*2);
    u16* wt_sqkv  = (u16*)alloc((size_t)768*2304*2);
    u16* wt_sproj = (u16*)alloc((size_t)768*768*2);
    u16* wt_fc1   = (u16*)alloc((size_t)768*3072*2);
    u16* wt_fc2   = (u16*)alloc((size_t)3072*768*2);
    // activation slots (aliased lifetimes)            total ~233 MB
    u16* slotA = (u16*)alloc((size_t)25280*2304*2);  // qkv_t / qkv_s / h1 halves (116.5 MB)
    u16* slotB = (u16*)alloc((size_t)25216*768*2);   // xt2 bf16 (38.7 MB)
    u16* slotD = (u16*)alloc((size_t)25216*768*2);   // ln_t/attn_t/ln_s/attn_s/ln2 (38.7 MB)
    u16* slotE = (u16*)alloc((size_t)25216*768*2);   // hp / rs bf16 (38.7 MB)
    // grand total ~252.8 MB; x_new lives in d_out (f32)

    dim3 tb(32, 8);
    transpose_w<<<dim3(72, 24), tb, 0, stream>>>(t_qkv_w,  wt_tqkv,  768, 2304);
    transpose_w<<<dim3(24, 24), tb, 0, stream>>>(t_proj_w, wt_tproj, 768, 768);
    transpose_w<<<dim3(24, 24), tb, 0, stream>>>(tfc_w,    wt_tfc,   768, 768);
    transpose_w<<<dim3(72, 24), tb, 0, stream>>>(s_qkv_w,  wt_sqkv,  768, 2304);
    transpose_w<<<dim3(24, 24), tb, 0, stream>>>(s_proj_w, wt_sproj, 768, 768);
    transpose_w<<<dim3(96, 24), tb, 0, stream>>>(fc1_w,    wt_fc1,   768, 3072);
    transpose_w<<<dim3(24, 96), tb, 0, stream>>>(fc2_w,    wt_fc2,   3072, 768);

    u16* lnT  = slotD;
    u16* qkvT = slotA;
    ln_kernel<0><<<25088/4, 256, 0, stream>>>(x, nullptr, tn1_w, tn1_b, lnT, 25088);
    gemm_bt<0,false,false,false,true,false><<<dim3(18,196), 256, 0, stream>>>(
        lnT, wt_tqkv, nullptr, nullptr, nullptr, qkvT, 2304, 768, 768, 768, 0);

    u16* attnT = slotD;
    attn_kernel<16,1,1><<<18816/4, 256, 0, stream>>>(qkvT, attnT, 18816);

    u16* hp = slotE;
    gemm_bt<0,true,false,false,true,false><<<dim3(6,196), 256, 0, stream>>>(
        attnT, wt_tproj, t_proj_b, nullptr, nullptr, hp, 768, 768, 768, 768, 0);

    u16* xt2 = slotB;   // tfc + bias + x-residual (skip-cls map) -> bf16
    gemm_bt<2,true,false,false,true,false><<<dim3(6,196), 256, 0, stream>>>(
        hp, wt_tfc, tfc_b, x, nullptr, xt2, 768, 768, 768, 768, 0);

    u16* lnS = slotD;
    ln_kernel<1><<<25216/4, 256, 0, stream>>>(x, xt2, n1_w, n1_b, lnS, 25216);

    u16* qkvS = slotA;
    gemm_bt<0,false,false,false,true,false><<<dim3(18,197), 256, 0, stream>>>(
        lnS, wt_sqkv, nullptr, nullptr, nullptr, qkvS, 2304, 768, 768, 768, 0);

    u16* attnS = slotD;
    attn_kernel<197,13,7><<<19968/4, 256, 0, stream>>>(qkvS, attnS, 19968);

    u16* rsb = slotE;
    gemm_bt<0,true,false,false,true,false><<<dim3(6,197), 256, 0, stream>>>(
        attnS, wt_sproj, s_proj_b, nullptr, nullptr, rsb, 768, 768, 768, 768, 0);

    float* xnew = out;                // x_new lives in d_out
    u16* ln2 = slotD;
    combine_ln2<<<25096/4, 256, 0, stream>>>(x, xt2, rsb, n2_w, n2_b, xnew, ln2, 25096);

    // MLP split into two hidden halves (h1 fits in slotA: 77.5 MB)
    u16* h1 = slotA;
    for (int half = 0; half < 2; ++half) {
        const u16* w1h = wt_fc1 + (size_t)half * 1536 * 768;   // rows [N-half][768]
        const float* b1h = fc1_b + half * 1536;
        gemm_bt<0,true,true,false,true,false><<<dim3(12,197), 256, 0, stream>>>(
            ln2, w1h, b1h, nullptr, nullptr, h1, 1536, 768, 768, 768, 0);
        const u16* w2h = wt_fc2 + (size_t)half * 1536;         // [768][3072] K-offset
        // out = xnew + y_half ; fc2 bias only once (half 0)
        if (half == 0)
            gemm_bt<1,true,false,true,false,true><<<dim3(6,197), 256, 0, stream>>>(
                h1, w2h, fc2_b, out, out, nullptr, 768, 1536, 1536, 3072, 25096);
        else
            gemm_bt<1,false,false,true,false,true><<<dim3(6,197), 256, 0, stream>>>(
                h1, w2h, nullptr, out, out, nullptr, 768, 1536, 1536, 3072, 25096);
    }
}

// Round 4
// 1388.522 us; speedup vs baseline: 1.0889x; 1.0597x over previous
//
#include <hip/hip_runtime.h>
#include <cstdint>

using u16 = unsigned short;
using u32 = unsigned int;

typedef __bf16 bf16x8 __attribute__((ext_vector_type(8)));
typedef float  floatx4 __attribute__((ext_vector_type(4)));

#define DEV static __device__ __forceinline__

// ---------- helpers ----------
DEV u16 f2bf(float f) {                 // f32 -> bf16 RNE
    u32 u = __float_as_uint(f);
    u += 0x7FFFu + ((u >> 16) & 1u);
    return (u16)(u >> 16);
}
DEV float bf2f(u16 v) { return __uint_as_float(((u32)v) << 16); }

DEV floatx4 mfma32(bf16x8 a, bf16x8 b, floatx4 c) {
    return __builtin_amdgcn_mfma_f32_16x16x32_bf16(a, b, c, 0, 0, 0);
}

DEV floatx4 fzero() { floatx4 z; z[0]=0.f; z[1]=0.f; z[2]=0.f; z[3]=0.f; return z; }

typedef __attribute__((address_space(3))) u32 as3_u32;
typedef __attribute__((address_space(1))) u32 as1_u32;

// async global->LDS, 16B per lane; LDS dest = wave-uniform base + lane*16.
// NOTE: direct C-style pointer casts = addrspacecast (strips LDS aperture).
DEV void async_ld16(const u16* g, u16* l) {
    __builtin_amdgcn_global_load_lds(
        (const as1_u32*)g, (as3_u32*)l, 16, 0, 0);
}

// ---------- weight transpose: W[K][N] f32 -> Wt[N][K] bf16 ----------
__global__ __launch_bounds__(256) void transpose_w(
    const float* __restrict__ W, u16* __restrict__ Wt, int K, int N)
{
    __shared__ float t[32][33];
    const int tx = threadIdx.x, ty = threadIdx.y;   // block 32x8
    const int gx = blockIdx.x * 32;                 // N dim
    const int gy = blockIdx.y * 32;                 // K dim
    #pragma unroll
    for (int i = 0; i < 4; ++i)
        t[ty + i*8][tx] = W[(size_t)(gy + ty + i*8) * N + gx + tx];
    __syncthreads();
    #pragma unroll
    for (int i = 0; i < 4; ++i)
        Wt[(size_t)(gx + ty + i*8) * K + gy + tx] = f2bf(t[tx][ty + i*8]);
}

// ---------- LayerNorm (wave per row, 4 rows/block), writes bf16 ----------
template<int MODE>
__global__ __launch_bounds__(256) void ln_kernel(
    const float* __restrict__ xp, const u16* __restrict__ xt2,
    const float* __restrict__ w, const float* __restrict__ b,
    u16* __restrict__ out, int nrows)
{
    const int row = blockIdx.x * 4 + (threadIdx.x >> 6);
    if (row >= nrows) return;
    const int lane = threadIdx.x & 63;
    float vals[12];
    if constexpr (MODE == 0) {
        const float* src = xp + (size_t)(row + row/3136 + 1) * 768;
        #pragma unroll
        for (int j = 0; j < 3; ++j) {
            float4 v = reinterpret_cast<const float4*>(src)[j*64 + lane];
            vals[j*4+0]=v.x; vals[j*4+1]=v.y; vals[j*4+2]=v.z; vals[j*4+3]=v.w;
        }
    } else {
        const int bt = row / 197;
        const int p  = row - bt * 197;
        const int b0 = bt >> 4, tt = bt & 15;
        if (p == 0) {
            const float* src = xp + (size_t)b0 * 3137 * 768;
            #pragma unroll
            for (int j = 0; j < 3; ++j) {
                float4 v = reinterpret_cast<const float4*>(src)[j*64 + lane];
                vals[j*4+0]=v.x; vals[j*4+1]=v.y; vals[j*4+2]=v.z; vals[j*4+3]=v.w;
            }
        } else {
            const u16* src = xt2 + (size_t)(b0*3136 + (p-1)*16 + tt) * 768;
            #pragma unroll
            for (int j = 0; j < 3; ++j) {
                uint2 q = reinterpret_cast<const uint2*>(src)[j*64 + lane];
                vals[j*4+0] = bf2f((u16)(q.x & 0xFFFF));
                vals[j*4+1] = bf2f((u16)(q.x >> 16));
                vals[j*4+2] = bf2f((u16)(q.y & 0xFFFF));
                vals[j*4+3] = bf2f((u16)(q.y >> 16));
            }
        }
    }
    float s = 0.f, ss = 0.f;
    #pragma unroll
    for (int e = 0; e < 12; ++e) { s += vals[e]; ss += vals[e]*vals[e]; }
    #pragma unroll
    for (int o = 32; o > 0; o >>= 1) { s += __shfl_xor(s, o); ss += __shfl_xor(ss, o); }
    const float mean = s * (1.f/768.f);
    const float var  = ss * (1.f/768.f) - mean*mean;
    const float rstd = rsqrtf(var + 1e-5f);
    #pragma unroll
    for (int j = 0; j < 3; ++j) {
        const int c4 = (j*64 + lane) * 4;
        union { u16 u[4]; uint2 q; } o;
        #pragma unroll
        for (int e = 0; e < 4; ++e)
            o.u[e] = f2bf((vals[j*4+e] - mean)*rstd*w[c4+e] + b[c4+e]);
        *reinterpret_cast<uint2*>(&out[(size_t)row*768 + c4]) = o.q;
    }
}

// ---------- combine: x_new = concat residuals (f32 -> d_out), then LN(n2) bf16 ----------
__global__ __launch_bounds__(256) void combine_ln2(
    const float* __restrict__ xp, const u16* __restrict__ xt2,
    const u16* __restrict__ rsb, const float* __restrict__ w, const float* __restrict__ b,
    float* __restrict__ xnew, u16* __restrict__ ln2, int nrows)
{
    const int row = blockIdx.x * 4 + (threadIdx.x >> 6);
    if (row >= nrows) return;
    const int lane = threadIdx.x & 63;
    const int b0 = row / 3137;
    const int j  = row - b0 * 3137;
    float vals[12];
    if (j == 0) {       // cls row: x[b,0] + mean_t rs[(b,t) seq, token 0]
        #pragma unroll
        for (int e = 0; e < 12; ++e) {
            const int c = e*64 + lane;
            float acc = 0.f;
            for (int t = 0; t < 16; ++t)
                acc += bf2f(rsb[(size_t)(b0*16 + t) * 197 * 768 + c]);
            vals[e] = xp[(size_t)row*768 + c] + acc * (1.f/16.f);
        }
    } else {
        const int n_idx = j - 1;
        const int hw = n_idx >> 4, tt = n_idx & 15;
        const u16* a  = xt2 + (size_t)(b0*3136 + n_idx) * 768;
        const u16* r2 = rsb + (size_t)((b0*16 + tt)*197 + 1 + hw) * 768;
        #pragma unroll
        for (int e = 0; e < 12; ++e) {
            const int c = e*64 + lane;
            vals[e] = bf2f(a[c]) + bf2f(r2[c]);
        }
    }
    float s = 0.f, ss = 0.f;
    #pragma unroll
    for (int e = 0; e < 12; ++e) { s += vals[e]; ss += vals[e]*vals[e]; }
    #pragma unroll
    for (int o = 32; o > 0; o >>= 1) { s += __shfl_xor(s, o); ss += __shfl_xor(ss, o); }
    const float mean = s * (1.f/768.f);
    const float var  = ss * (1.f/768.f) - mean*mean;
    const float rstd = rsqrtf(var + 1e-5f);
    #pragma unroll
    for (int e = 0; e < 12; ++e) {
        const int c = e*64 + lane;
        xnew[(size_t)row*768 + c] = vals[e];
        ln2[(size_t)row*768 + c]  = f2bf((vals[e] - mean)*rstd*w[c] + b[c]);
    }
}

// ---------- GEMM: C[M,N] = act(A[M,K]bf16 @ B + bias (+resid)) ----------
// Bt is B^T bf16 [N][ldb]. 128x128 tile, BK=32, 4 waves of 4x4 16x16x32 MFMAs.
// XOR-swizzled LDS: chunk (row,kc) lives at physical chunk kc^((row>>1)&3).
//   -> ds_read_b128 bank spread <=2-way (free, m136); was 8-way.
// Staging: lane's GLOBAL source is permuted (LDS dest must stay lane-linear).
// OUTB epilogue: stage C tile in LDS, store 128B-line uint4 (no partial-line RMW).
// RESID: 0 none, 1 f32 resid[row*N+col], 2 f32 x-skip-cls resid[(row+row/3136+1)*768+col]
template<int RESID, bool BIAS, bool GELU_ACT, bool OUTF, bool OUTB, bool MASKM>
__global__ __launch_bounds__(256) void gemm_bt(
    const u16* __restrict__ A, const u16* __restrict__ Bt,
    const float* __restrict__ bias, const float* __restrict__ resid,
    float* __restrict__ Cf, u16* __restrict__ Cb,
    int N, int K, int lda, int ldb, int Mvalid)
{
    __shared__ __attribute__((aligned(16))) u16 smem[2*128*32];
    u16* As = smem;               // 8 KB
    u16* Bs = smem + 128*32;      // 8 KB
    const int tid  = threadIdx.x;
    const int wave = tid >> 6;
    const int lane = tid & 63;
    const int m15  = lane & 15;
    const int quad = lane >> 4;
    const int wm = wave >> 1, wn = wave & 1;
    const long m0 = (long)blockIdx.y * 128;   // M-tile (slow dim)
    const long n0 = (long)blockIdx.x * 128;   // N-tile (fast dim -> A reuse)

    // staging slots: slot s holds global chunk (row=s>>2, kc=(s&3)^((s>>3)&3))
    const int s0 = wave*128 + lane;
    const int s1 = s0 + 64;
    const int kc0 = (s0 & 3) ^ ((s0 >> 3) & 3);
    const int kc1 = (s1 & 3) ^ ((s1 >> 3) & 3);
    const u16* Ag0 = A  + (size_t)(m0 + (s0 >> 2)) * lda + kc0 * 8;
    const u16* Ag1 = A  + (size_t)(m0 + (s1 >> 2)) * lda + kc1 * 8;
    const u16* Bg0 = Bt + (size_t)(n0 + (s0 >> 2)) * ldb + kc0 * 8;
    const u16* Bg1 = Bt + (size_t)(n0 + (s1 >> 2)) * ldb + kc1 * 8;
    u16* Al0 = &As[(wave*2 + 0) * 512];       // + lane*16B implicit in DMA
    u16* Al1 = &As[(wave*2 + 1) * 512];
    u16* Bl0 = &Bs[(wave*2 + 0) * 512];
    u16* Bl1 = &Bs[(wave*2 + 1) * 512];

    // reader swizzle: row-invariant across fragments (rows differ by mult of 16)
    const int swz = (quad ^ ((m15 >> 1) & 3)) * 8;

    floatx4 acc[4][4];
    #pragma unroll
    for (int i = 0; i < 4; ++i)
        #pragma unroll
        for (int j = 0; j < 4; ++j) acc[i][j] = fzero();

    for (int k0 = 0; k0 < K; k0 += 32) {
        __syncthreads();                       // previous tile's reads done
        async_ld16(Ag0 + k0, Al0);
        async_ld16(Ag1 + k0, Al1);
        async_ld16(Bg0 + k0, Bl0);
        async_ld16(Bg1 + k0, Bl1);
        __syncthreads();                       // drains vmcnt -> tiles visible
        bf16x8 af[4], bf[4];
        #pragma unroll
        for (int i = 0; i < 4; ++i)
            af[i] = *reinterpret_cast<const bf16x8*>(&As[(wm*64 + i*16 + m15)*32 + swz]);
        #pragma unroll
        for (int j = 0; j < 4; ++j)
            bf[j] = *reinterpret_cast<const bf16x8*>(&Bs[(wn*64 + j*16 + m15)*32 + swz]);
        #pragma unroll
        for (int i = 0; i < 4; ++i)
            #pragma unroll
            for (int j = 0; j < 4; ++j)
                acc[i][j] = mfma32(af[i], bf[j], acc[i][j]);
    }

    // epilogue: D row=(quad*4+r), col=lane&15 within each 16x16 tile
    float bv[4];
    #pragma unroll
    for (int j = 0; j < 4; ++j)
        bv[j] = BIAS ? bias[n0 + wn*64 + j*16 + m15] : 0.f;

    if constexpr (OUTB) {
        // stage through LDS, write 128B-line-aligned uint4
        u16* cbuf = smem + wave * 2048;        // 4 KB per wave
        #pragma unroll
        for (int p = 0; p < 2; ++p) {
            __syncthreads();                   // cbuf region free (K-loop / prev pass)
            #pragma unroll
            for (int ii = 0; ii < 2; ++ii) {
                const int i = p*2 + ii;
                #pragma unroll
                for (int j = 0; j < 4; ++j) {
                    #pragma unroll
                    for (int r = 0; r < 4; ++r) {
                        const long row = m0 + wm*64 + i*16 + quad*4 + r;
                        float v = acc[i][j][r] + bv[j];
                        if constexpr (RESID == 1)
                            v += resid[(size_t)row * N + (n0 + wn*64 + j*16 + m15)];
                        if constexpr (RESID == 2)
                            v += resid[(size_t)(row + row/3136 + 1) * 768 + (n0 + wn*64 + j*16 + m15)];
                        if constexpr (GELU_ACT)
                            v = 0.5f * v * (1.f + erff(v * 0.70710678118f));
                        cbuf[(ii*16 + quad*4 + r)*64 + j*16 + m15] = f2bf(v);
                    }
                }
            }
            __syncthreads();                   // cbuf visible to whole wave set
            #pragma unroll
            for (int it = 0; it < 4; ++it) {
                const int lr = (lane >> 3) + it*8;
                const int cc = lane & 7;
                const uint4 val = *reinterpret_cast<const uint4*>(&cbuf[lr*64 + cc*8]);
                const long grow = m0 + wm*64 + p*32 + lr;
                *reinterpret_cast<uint4*>(&Cb[(size_t)grow * N + n0 + wn*64 + cc*8]) = val;
            }
        }
    } else {
        #pragma unroll
        for (int j = 0; j < 4; ++j) {
            const long col = n0 + wn*64 + j*16 + m15;
            #pragma unroll
            for (int i = 0; i < 4; ++i) {
                const long rowb = m0 + wm*64 + i*16 + quad*4;
                #pragma unroll
                for (int r = 0; r < 4; ++r) {
                    const long row = rowb + r;
                    if constexpr (MASKM) { if (row >= Mvalid) continue; }
                    float v = acc[i][j][r] + bv[j];
                    if constexpr (RESID == 1) v += resid[(size_t)row * N + col];
                    if constexpr (RESID == 2) v += resid[(size_t)(row + row/3136 + 1) * 768 + col];
                    if constexpr (GELU_ACT)   v = 0.5f * v * (1.f + erff(v * 0.70710678118f));
                    if constexpr (OUTF) Cf[(size_t)row * N + col] = v;
                }
            }
        }
    }
}

// ---------- fused attention (flash-style), one wave per (seq, head, q-tile) ----------
template<int S, int NQ, int NIT>
__global__ __launch_bounds__(256) void attn_kernel(
    const u16* __restrict__ qkv, u16* __restrict__ out, int ntask)
{
    __shared__ __attribute__((aligned(16))) u16 P_lds[4][16*32];
    const int wave = threadIdx.x >> 6;
    const int lane = threadIdx.x & 63;
    const int task = blockIdx.x * 4 + wave;
    if (task >= ntask) return;
    const int seq  = task / (12 * NQ);
    const int rem  = task - seq * (12 * NQ);
    const int head = rem / NQ;
    const int qt   = rem - head * NQ;
    const int m15  = lane & 15;
    const int quad = lane >> 4;
    const size_t base = (size_t)seq * S;

    const u16* qp = qkv + (base + qt*16 + m15) * 2304 + head*64 + quad*8;
    const bf16x8 Qf0 = *reinterpret_cast<const bf16x8*>(qp);
    const bf16x8 Qf1 = *reinterpret_cast<const bf16x8*>(qp + 32);

    floatx4 Oacc[4];
    #pragma unroll
    for (int c = 0; c < 4; ++c) Oacc[c] = fzero();
    float mrun = -__builtin_inff();
    float lrun = 0.f;
    u16* P = &P_lds[wave][0];

    for (int it = 0; it < NIT; ++it) {
        const int j0 = it * 32;
        floatx4 st[2];
        #pragma unroll
        for (int h2 = 0; h2 < 2; ++h2) {
            const u16* kp = qkv + (base + j0 + h2*16 + m15) * 2304 + 768 + head*64 + quad*8;
            const bf16x8 K0 = *reinterpret_cast<const bf16x8*>(kp);
            const bf16x8 K1 = *reinterpret_cast<const bf16x8*>(kp + 32);
            floatx4 z = fzero();
            z = mfma32(K0, Qf0, z);
            st[h2] = mfma32(K1, Qf1, z);
        }
        float sc[8];
        #pragma unroll
        for (int h2 = 0; h2 < 2; ++h2)
            #pragma unroll
            for (int r = 0; r < 4; ++r) {
                const int jj = j0 + h2*16 + quad*4 + r;
                sc[h2*4+r] = (jj < S) ? st[h2][r] * 0.125f : -__builtin_inff();
            }
        float tmax = sc[0];
        #pragma unroll
        for (int k = 1; k < 8; ++k) tmax = fmaxf(tmax, sc[k]);
        tmax = fmaxf(tmax, __shfl_xor(tmax, 16));
        tmax = fmaxf(tmax, __shfl_xor(tmax, 32));
        const float mnew = fmaxf(mrun, tmax);
        float p[8], tsum = 0.f;
        #pragma unroll
        for (int k = 0; k < 8; ++k) { p[k] = __expf(sc[k] - mnew); tsum += p[k]; }
        tsum += __shfl_xor(tsum, 16);
        tsum += __shfl_xor(tsum, 32);
        const float alpha = __expf(mrun - mnew);
        lrun = lrun * alpha + tsum;
        mrun = mnew;
        #pragma unroll
        for (int r = 0; r < 4; ++r) {             // rescale O rows (row = quad*4+r)
            const float ar = __shfl(alpha, quad*4 + r);
            #pragma unroll
            for (int c = 0; c < 4; ++c) Oacc[c][r] *= ar;
        }
        // P round-trip through LDS: C-layout -> A-operand layout
        #pragma unroll
        for (int h2 = 0; h2 < 2; ++h2)
            #pragma unroll
            for (int r = 0; r < 4; ++r)
                P[m15*32 + h2*16 + quad*4 + r] = f2bf(p[h2*4+r]);
        const bf16x8 Pf = *reinterpret_cast<const bf16x8*>(&P[m15*32 + quad*8]);
        #pragma unroll
        for (int c = 0; c < 4; ++c) {             // V in B-operand layout (scattered u16)
            union { u16 u[8]; bf16x8 v; } vf;
            #pragma unroll
            for (int jj2 = 0; jj2 < 8; ++jj2)
                vf.u[jj2] = qkv[(base + j0 + quad*8 + jj2) * 2304 + 1536 + head*64 + c*16 + m15];
            Oacc[c] = mfma32(Pf, vf.v, Oacc[c]);
        }
    }
    const float linv_self = 1.f / lrun;
    #pragma unroll
    for (int r = 0; r < 4; ++r) {
        const int prow = qt*16 + quad*4 + r;
        const float linv = __shfl(linv_self, quad*4 + r);
        if (prow < S) {
            u16* op = out + (base + prow) * 768 + head*64 + m15;
            #pragma unroll
            for (int c = 0; c < 4; ++c) op[c*16] = f2bf(Oacc[c][r] * linv);
        }
    }
}

// ---------- host ----------
extern "C" void kernel_launch(void* const* d_in, const int* in_sizes, int n_in,
                              void* d_out, int out_size, void* d_ws, size_t ws_size,
                              hipStream_t stream)
{
    (void)in_sizes; (void)n_in; (void)out_size; (void)ws_size;
    const float* x        = (const float*)d_in[0];
    const float* tn1_w    = (const float*)d_in[1];
    const float* tn1_b    = (const float*)d_in[2];
    const float* t_qkv_w  = (const float*)d_in[3];
    const float* t_proj_w = (const float*)d_in[4];
    const float* t_proj_b = (const float*)d_in[5];
    const float* tfc_w    = (const float*)d_in[6];
    const float* tfc_b    = (const float*)d_in[7];
    const float* n1_w     = (const float*)d_in[8];
    const float* n1_b     = (const float*)d_in[9];
    const float* s_qkv_w  = (const float*)d_in[10];
    const float* s_proj_w = (const float*)d_in[11];
    const float* s_proj_b = (const float*)d_in[12];
    const float* n2_w     = (const float*)d_in[13];
    const float* n2_b     = (const float*)d_in[14];
    const float* fc1_w    = (const float*)d_in[15];
    const float* fc1_b    = (const float*)d_in[16];
    const float* fc2_w    = (const float*)d_in[17];
    const float* fc2_b    = (const float*)d_in[18];
    float* out = (float*)d_out;

    char* ws = (char*)d_ws;
    size_t off = 0;
    auto alloc = [&](size_t bytes) -> void* {
        void* p = ws + off;
        off += (bytes + 255) & ~(size_t)255;
        return p;
    };
    // weights (bf16, transposed to [N][K])           total ~20.1 MB
    u16* wt_tqkv  = (u16*)alloc((size_t)768*2304*2);
    u16* wt_tproj = (u16*)alloc((size_t)768*768*2);
    u16* wt_tfc   = (u16*)alloc((size_t)768*768*2);
    u16* wt_sqkv  = (u16*)alloc((size_t)768*2304*2);
    u16* wt_sproj = (u16*)alloc((size_t)768*768*2);
    u16* wt_fc1   = (u16*)alloc((size_t)768*3072*2);
    u16* wt_fc2   = (u16*)alloc((size_t)3072*768*2);
    // activation slots (aliased lifetimes)            total ~233 MB
    u16* slotA = (u16*)alloc((size_t)25280*2304*2);  // qkv_t / qkv_s / h1 halves (116.5 MB)
    u16* slotB = (u16*)alloc((size_t)25216*768*2);   // xt2 bf16 (38.7 MB)
    u16* slotD = (u16*)alloc((size_t)25216*768*2);   // ln_t/attn_t/ln_s/attn_s/ln2 (38.7 MB)
    u16* slotE = (u16*)alloc((size_t)25216*768*2);   // hp / rs bf16 (38.7 MB)
    // grand total ~252.8 MB; x_new lives in d_out (f32)

    dim3 tb(32, 8);
    transpose_w<<<dim3(72, 24), tb, 0, stream>>>(t_qkv_w,  wt_tqkv,  768, 2304);
    transpose_w<<<dim3(24, 24), tb, 0, stream>>>(t_proj_w, wt_tproj, 768, 768);
    transpose_w<<<dim3(24, 24), tb, 0, stream>>>(tfc_w,    wt_tfc,   768, 768);
    transpose_w<<<dim3(72, 24), tb, 0, stream>>>(s_qkv_w,  wt_sqkv,  768, 2304);
    transpose_w<<<dim3(24, 24), tb, 0, stream>>>(s_proj_w, wt_sproj, 768, 768);
    transpose_w<<<dim3(96, 24), tb, 0, stream>>>(fc1_w,    wt_fc1,   768, 3072);
    transpose_w<<<dim3(24, 96), tb, 0, stream>>>(fc2_w,    wt_fc2,   3072, 768);

    u16* lnT  = slotD;
    u16* qkvT = slotA;
    ln_kernel<0><<<25088/4, 256, 0, stream>>>(x, nullptr, tn1_w, tn1_b, lnT, 25088);
    gemm_bt<0,false,false,false,true,false><<<dim3(18,196), 256, 0, stream>>>(
        lnT, wt_tqkv, nullptr, nullptr, nullptr, qkvT, 2304, 768, 768, 768, 0);

    u16* attnT = slotD;
    attn_kernel<16,1,1><<<18816/4, 256, 0, stream>>>(qkvT, attnT, 18816);

    u16* hp = slotE;
    gemm_bt<0,true,false,false,true,false><<<dim3(6,196), 256, 0, stream>>>(
        attnT, wt_tproj, t_proj_b, nullptr, nullptr, hp, 768, 768, 768, 768, 0);

    u16* xt2 = slotB;   // tfc + bias + x-residual (skip-cls map) -> bf16
    gemm_bt<2,true,false,false,true,false><<<dim3(6,196), 256, 0, stream>>>(
        hp, wt_tfc, tfc_b, x, nullptr, xt2, 768, 768, 768, 768, 0);

    u16* lnS = slotD;
    ln_kernel<1><<<25216/4, 256, 0, stream>>>(x, xt2, n1_w, n1_b, lnS, 25216);

    u16* qkvS = slotA;
    gemm_bt<0,false,false,false,true,false><<<dim3(18,197), 256, 0, stream>>>(
        lnS, wt_sqkv, nullptr, nullptr, nullptr, qkvS, 2304, 768, 768, 768, 0);

    u16* attnS = slotD;
    attn_kernel<197,13,7><<<19968/4, 256, 0, stream>>>(qkvS, attnS, 19968);

    u16* rsb = slotE;
    gemm_bt<0,true,false,false,true,false><<<dim3(6,197), 256, 0, stream>>>(
        attnS, wt_sproj, s_proj_b, nullptr, nullptr, rsb, 768, 768, 768, 768, 0);

    float* xnew = out;                // x_new lives in d_out
    u16* ln2 = slotD;
    combine_ln2<<<25096/4, 256, 0, stream>>>(x, xt2, rsb, n2_w, n2_b, xnew, ln2, 25096);

    // MLP split into two hidden halves (h1 fits in slotA: 77.5 MB)
    u16* h1 = slotA;
    for (int half = 0; half < 2; ++half) {
        const u16* w1h = wt_fc1 + (size_t)half * 1536 * 768;   // rows [N-half][768]
        const float* b1h = fc1_b + half * 1536;
        gemm_bt<0,true,true,false,true,false><<<dim3(12,197), 256, 0, stream>>>(
            ln2, w1h, b1h, nullptr, nullptr, h1, 1536, 768, 768, 768, 0);
        const u16* w2h = wt_fc2 + (size_t)half * 1536;         // [768][3072] K-offset
        // out = xnew + y_half ; fc2 bias only once (half 0)
        if (half == 0)
            gemm_bt<1,true,false,true,false,true><<<dim3(6,197), 256, 0, stream>>>(
                h1, w2h, fc2_b, out, out, nullptr, 768, 1536, 1536, 3072, 25096);
        else
            gemm_bt<1,false,false,true,false,true><<<dim3(6,197), 256, 0, stream>>>(
                h1, w2h, nullptr, out, out, nullptr, 768, 1536, 1536, 3072, 25096);
    }
}